// Round 11
// baseline (179.679 us; speedup 1.0000x reference)
//
#include <hip/hip_runtime.h>
#include <math.h>

#define BATCH 4
#define NPTS 4096
#define DF 64
#define ROWB 128               // bytes per point row in bf16
#define TILE 128               // cols per staged tile
#define MC 4                   // col chunks
#define CHUNK (NPTS / MC)      // 1024
#define ITERS (CHUNK / TILE)   // 8
#define RW 64                  // rows per block
#define INV_T 100.0f
#define MARGIN 0.16f           // skipped weights < exp(-16) ~ 1.1e-7
#define HM2C (0.5f * MARGIN * MARGIN)
#define SCALE (1.0f / 16384.0f)

typedef float  f32x4 __attribute__((ext_vector_type(4)));
typedef short  s16x8 __attribute__((ext_vector_type(8)));
typedef unsigned short u16;

// ws layout (~5.7 MB)
#define SZ_B   (BATCH * NPTS * DF * 2)   // bf16 array: 2 MB
#define SZ_N   (BATCH * NPTS * 4)        // norm array: 64 KB
#define OFF_XB 0
#define OFF_YB (OFF_XB + SZ_B)
#define OFF_X2 (OFF_YB + SZ_B)
#define OFF_Y2 (OFF_X2 + SZ_N)
#define OFF_PART (OFF_Y2 + SZ_N)         // [dirb][MC][NPTS][3] floats: 1.5 MB

__device__ __forceinline__ u16 f2bf(float f) {
    unsigned u = __float_as_uint(f);
    unsigned r = (u + 0x7fffu + ((u >> 16) & 1u)) >> 16;   // RNE
    return (u16)r;
}

// async 16B global -> LDS (DMA, no VGPR round-trip)
__device__ __forceinline__ void async16(void* lds, const void* g) {
    __builtin_amdgcn_global_load_lds(
        (const __attribute__((address_space(1))) unsigned int*)g,
        (__attribute__((address_space(3))) unsigned int*)lds, 16, 0, 0);
}

// fp32 -> bf16 (XOR-swizzled row layout: byte ^= (point&7)<<4) + fp32 norms.
__global__ __launch_bounds__(256) void prep_kernel(const float* __restrict__ X,
                                                   const float* __restrict__ Y,
                                                   u16* __restrict__ xb, u16* __restrict__ yb,
                                                   float* __restrict__ x2, float* __restrict__ y2,
                                                   float* __restrict__ out) {
    if (blockIdx.x == 0 && blockIdx.y == 0 && threadIdx.x == 0) out[0] = 0.0f;
    const float* src = blockIdx.y ? Y : X;
    u16* dstb   = blockIdx.y ? yb : xb;
    float* dstn = blockIdx.y ? y2 : x2;
    int g = blockIdx.x * 256 + threadIdx.x;
    int p = g >> 4;                       // point 0..16383
    int sub = g & 15;                     // 8B chunk within row
    float4 v = ((const float4*)src)[(size_t)p * 16 + sub];
    float n4 = v.x * v.x + v.y * v.y + v.z * v.z + v.w * v.w;
    #pragma unroll
    for (int m = 1; m < 16; m <<= 1) n4 += __shfl_xor(n4, m, 16);
    ushort4 hh;
    hh.x = f2bf(v.x); hh.y = f2bf(v.y); hh.z = f2bf(v.z); hh.w = f2bf(v.w);
    int byteoff = (sub << 3) ^ ((p & 7) << 4);   // swizzle (XOR bits 4..6)
    *(ushort4*)((char*)dstb + (size_t)p * ROWB + byteoff) = hh;
    if (sub == 0) dstn[p] = n4;
}

// Two-phase partial softmin. Block = 64 rows x 1024 cols of one (b, dir).
// 1x4 col-split wave tiling: all 4 waves share rows, each owns a 32-col slice
// of the 128-col staged tile => B ds_read redundancy 1x. MFMA C-input seeded
// with -y2/2 so u = acc[r] directly (no epilogue fma, no acc zero-init).
__attribute__((amdgpu_waves_per_eu(4, 4)))
__global__ __launch_bounds__(256) void softmin_fused(const u16* __restrict__ xb,
                                                     const u16* __restrict__ yb,
                                                     const float* __restrict__ x2g,
                                                     const float* __restrict__ y2g,
                                                     float* __restrict__ part) {
    __shared__ u16 ys[2][TILE * DF];     // 2 x 16 KB double buffer
    __shared__ float xchg[2][4][64];     // cross-wave max / sum merge
    __shared__ float dthr_s[64];

    const int tid = threadIdx.x;
    // XCD-bijective swizzle (2048 = 8 XCDs x 256): per-XCD working set = one
    // (dir,b) pair ~1 MB -> L2-resident.
    const int bid = blockIdx.x;
    const int swz = (bid & 7) * 256 + (bid >> 3);
    const int dirb = swz >> 8;           // 0..7 = dir*4 + b
    const int rem  = swz & 255;
    const int nt   = rem >> 2;           // row tile 0..63
    const int cs   = rem & 3;            // col chunk 0..3
    const int b    = dirb & 3;
    const int dir  = dirb >> 2;

    const int w = tid >> 6;              // wave -> 32-col slice of tile
    const int h = (tid >> 4) & 3;        // k-octet / D-row group
    const int c = tid & 15;              // fragment lane slot

    const u16 *rowsrc, *colsrc; const float *rn, *cn;
    if (dir == 0) { rowsrc = xb; colsrc = yb; rn = x2g; cn = y2g; }
    else          { rowsrc = yb; colsrc = xb; rn = y2g; cn = x2g; }

    const size_t bpts = (size_t)b * NPTS;
    const char* rbase = (const char*)(rowsrc + (bpts + (size_t)nt * RW) * DF);
    const char* cbase = (const char*)(colsrc + (bpts + (size_t)cs * CHUNK) * DF);
    const float* cnb = cn + bpts + (size_t)cs * CHUNK;
    const float* rnb = rn + bpts + (size_t)nt * RW;

    // col points and B fragment offsets for this wave's two 16-col groups
    const int p0 = w * 32 + c, p1 = w * 32 + 16 + c;
    const int bo00 = p0 * ROWB + ((h * 16) ^ ((p0 & 7) << 4));
    const int bo01 = p0 * ROWB + ((h * 16 + 64) ^ ((p0 & 7) << 4));
    const int bo10 = p1 * ROWB + ((h * 16) ^ ((p1 & 7) << 4));
    const int bo11 = p1 * ROWB + ((h * 16 + 64) ^ ((p1 & 7) << 4));

    // ---- prologue: DMA first tile; A-frags direct from pre-swizzled global ----
    #pragma unroll
    for (int q = 0; q < 4; ++q) {
        int e = q * 256 + tid;
        async16((char*)ys[0] + e * 16, cbase + e * 16);
    }
    float cy0 = cnb[p0], cy1 = cnb[p1];

    s16x8 af[4][2];                      // rows st*16 + c (all 64 block rows)
    #pragma unroll
    for (int st = 0; st < 4; ++st) {
        int rr = st * 16 + c;
        #pragma unroll
        for (int kp = 0; kp < 2; ++kp) {
            int o = (h * 16 + kp * 64) ^ ((rr & 7) << 4);
            af[st][kp] = *(const s16x8*)(rbase + rr * ROWB + o);
        }
    }

    float mx[4][4];
    #pragma unroll
    for (int st = 0; st < 4; ++st)
        #pragma unroll
        for (int r = 0; r < 4; ++r) mx[st][r] = -INFINITY;

    // ================= PASS 1: exact chunk max of u = x.y - y2/2 =================
    for (int it = 0; it < ITERS; ++it) {
        __syncthreads();                 // drains DMA (vmcnt 0) + barrier
        float m0 = -0.5f * cy0, m1 = -0.5f * cy1;
        if (it + 1 < ITERS) {
            const char* nsrc = cbase + (size_t)(it + 1) * TILE * ROWB;
            char* nbuf = (char*)ys[(it + 1) & 1];
            #pragma unroll
            for (int q = 0; q < 4; ++q) {
                int e = q * 256 + tid;
                async16(nbuf + e * 16, nsrc + e * 16);
            }
            cy0 = cnb[(it + 1) * TILE + p0];
            cy1 = cnb[(it + 1) * TILE + p1];
        }
        const char* bptr = (const char*)ys[it & 1];
        s16x8 bf00 = *(const s16x8*)(bptr + bo00);
        s16x8 bf01 = *(const s16x8*)(bptr + bo01);
        s16x8 bf10 = *(const s16x8*)(bptr + bo10);
        s16x8 bf11 = *(const s16x8*)(bptr + bo11);
        f32x4 q0 = {m0, m0, m0, m0}, q1 = {m1, m1, m1, m1};
        #pragma unroll
        for (int st = 0; st < 4; ++st) {
            f32x4 a0 = __builtin_amdgcn_mfma_f32_16x16x32_bf16(af[st][0], bf00, q0, 0, 0, 0);
            a0 = __builtin_amdgcn_mfma_f32_16x16x32_bf16(af[st][1], bf01, a0, 0, 0, 0);
            f32x4 a1 = __builtin_amdgcn_mfma_f32_16x16x32_bf16(af[st][0], bf10, q1, 0, 0, 0);
            a1 = __builtin_amdgcn_mfma_f32_16x16x32_bf16(af[st][1], bf11, a1, 0, 0, 0);
            #pragma unroll
            for (int r = 0; r < 4; ++r)
                mx[st][r] = fmaxf(mx[st][r], fmaxf(a0[r], a1[r]));   // v_max3
        }
    }

    // butterfly max within 16 col-lanes, then merge across the 4 waves
    #pragma unroll
    for (int st = 0; st < 4; ++st)
        #pragma unroll
        for (int r = 0; r < 4; ++r)
            #pragma unroll
            for (int m = 1; m < 16; m <<= 1)
                mx[st][r] = fmaxf(mx[st][r], __shfl_xor(mx[st][r], m, 16));
    if (c == 0) {
        #pragma unroll
        for (int st = 0; st < 4; ++st) {
            f32x4 v = {mx[st][0], mx[st][1], mx[st][2], mx[st][3]};
            *(f32x4*)&xchg[0][w][st * 16 + 4 * h] = v;
        }
    }
    __syncthreads();

    float gthr[4][4], ssum[4][4], tsum[4][4];
    #pragma unroll
    for (int st = 0; st < 4; ++st) {
        #pragma unroll
        for (int w2 = 0; w2 < 4; ++w2) {
            f32x4 o = *(const f32x4*)&xchg[0][w2][st * 16 + 4 * h];
            #pragma unroll
            for (int r = 0; r < 4; ++r) mx[st][r] = fmaxf(mx[st][r], o[r]);
        }
        f32x4 xv = *(const f32x4*)(rnb + st * 16 + 4 * h);
        #pragma unroll
        for (int r = 0; r < 4; ++r) {
            float d2m = fmaf(-2.f, mx[st][r], xv[r]);      // exact min d^2
            float mval = sqrtf(fmaxf(d2m, 0.f));
            gthr[st][r] = mx[st][r] - MARGIN * mval - HM2C;  // u>gthr <=> d<mval+M
            ssum[st][r] = 0.f; tsum[st][r] = 0.f;
            if (w == 0 && c == 0)
                dthr_s[st * 16 + 4 * h + r] = sqrtf(fmaf(-2.f, gthr[st][r], xv[r]));
        }
    }

    // re-prologue for pass 2 (ys[0] reads all complete before the merge barrier)
    #pragma unroll
    for (int q = 0; q < 4; ++q) {
        int e = q * 256 + tid;
        async16((char*)ys[0] + e * 16, cbase + e * 16);
    }
    cy0 = cnb[p0]; cy1 = cnb[p1];

    // ================= PASS 2: gated weighted sums (ref = d_thr) =================
    for (int it = 0; it < ITERS; ++it) {
        __syncthreads();
        float m0 = -0.5f * cy0, m1 = -0.5f * cy1;
        if (it + 1 < ITERS) {
            const char* nsrc = cbase + (size_t)(it + 1) * TILE * ROWB;
            char* nbuf = (char*)ys[(it + 1) & 1];
            #pragma unroll
            for (int q = 0; q < 4; ++q) {
                int e = q * 256 + tid;
                async16(nbuf + e * 16, nsrc + e * 16);
            }
            cy0 = cnb[(it + 1) * TILE + p0];
            cy1 = cnb[(it + 1) * TILE + p1];
        }
        const char* bptr = (const char*)ys[it & 1];
        s16x8 bf00 = *(const s16x8*)(bptr + bo00);
        s16x8 bf01 = *(const s16x8*)(bptr + bo01);
        s16x8 bf10 = *(const s16x8*)(bptr + bo10);
        s16x8 bf11 = *(const s16x8*)(bptr + bo11);
        f32x4 q0 = {m0, m0, m0, m0}, q1 = {m1, m1, m1, m1};
        #pragma unroll
        for (int st = 0; st < 4; ++st) {
            f32x4 a0 = __builtin_amdgcn_mfma_f32_16x16x32_bf16(af[st][0], bf00, q0, 0, 0, 0);
            a0 = __builtin_amdgcn_mfma_f32_16x16x32_bf16(af[st][1], bf01, a0, 0, 0, 0);
            f32x4 a1 = __builtin_amdgcn_mfma_f32_16x16x32_bf16(af[st][0], bf10, q1, 0, 0, 0);
            a1 = __builtin_amdgcn_mfma_f32_16x16x32_bf16(af[st][1], bf11, a1, 0, 0, 0);
            #pragma unroll
            for (int r = 0; r < 4; ++r) {
                if (__any((a0[r] > gthr[st][r]) | (a1[r] > gthr[st][r]))) {
                    f32x4 xv = *(const f32x4*)(rnb + st * 16 + 4 * h);
                    float dthr = sqrtf(fmaf(-2.f, gthr[st][r], xv[r]));   // = mval+M
                    float d0 = sqrtf(fmaxf(fmaf(-2.f, a0[r], xv[r]), 0.f));
                    float d1 = sqrtf(fmaxf(fmaf(-2.f, a1[r], xv[r]), 0.f));
                    float e0 = __expf(INV_T * (dthr - d0));   // ->0 if far
                    float e1 = __expf(INV_T * (dthr - d1));
                    ssum[st][r] += e0 + e1;
                    tsum[st][r] = fmaf(e0, d0, fmaf(e1, d1, tsum[st][r]));
                }
            }
        }
    }

    // butterfly sums within 16 col-lanes; merge across waves; write part
    #pragma unroll
    for (int st = 0; st < 4; ++st)
        #pragma unroll
        for (int r = 0; r < 4; ++r)
            #pragma unroll
            for (int m = 1; m < 16; m <<= 1) {
                ssum[st][r] += __shfl_xor(ssum[st][r], m, 16);
                tsum[st][r] += __shfl_xor(tsum[st][r], m, 16);
            }
    if (c == 0) {
        #pragma unroll
        for (int st = 0; st < 4; ++st) {
            f32x4 vs = {ssum[st][0], ssum[st][1], ssum[st][2], ssum[st][3]};
            f32x4 vt = {tsum[st][0], tsum[st][1], tsum[st][2], tsum[st][3]};
            *(f32x4*)&xchg[0][w][st * 16 + 4 * h] = vs;
            *(f32x4*)&xchg[1][w][st * 16 + 4 * h] = vt;
        }
    }
    __syncthreads();
    if (tid < RW) {                      // one thread per row
        float S = xchg[0][0][tid] + xchg[0][1][tid] + xchg[0][2][tid] + xchg[0][3][tid];
        float T = xchg[1][0][tid] + xchg[1][1][tid] + xchg[1][2][tid] + xchg[1][3][tid];
        int row = nt * RW + tid;
        size_t idx = (((size_t)dirb * MC + cs) * NPTS + row) * 3;
        part[idx + 0] = dthr_s[tid];
        part[idx + 1] = S;
        part[idx + 2] = T;
    }
}

// Merge MC partial states per row, cube, reduce, atomicAdd into out[0].
__global__ __launch_bounds__(256) void merge_kernel(const float* __restrict__ part,
                                                    float* __restrict__ out) {
    __shared__ float red[4];
    int g = blockIdx.x * 256 + threadIdx.x;   // dirb*4096 + row
    int dirb = g >> 12;
    int row  = g & 4095;
    float nm = INFINITY;
    float mnv[MC], sv[MC], tv[MC];
    #pragma unroll
    for (int k = 0; k < MC; ++k) {
        const float* p = part + (((size_t)dirb * MC + k) * NPTS + row) * 3;
        mnv[k] = p[0]; sv[k] = p[1]; tv[k] = p[2];
        nm = fminf(nm, mnv[k]);
    }
    float S = 0.f, T = 0.f;
    #pragma unroll
    for (int k = 0; k < MC; ++k) {
        float cw = __expf(INV_T * (nm - mnv[k]));
        S += sv[k] * cw;
        T += tv[k] * cw;
    }
    float sm = T / S;
    float v = sm * sm * sm * SCALE;
    #pragma unroll
    for (int m = 1; m < 64; m <<= 1) v += __shfl_xor(v, m, 64);
    if ((threadIdx.x & 63) == 0) red[threadIdx.x >> 6] = v;
    __syncthreads();
    if (threadIdx.x == 0) atomicAdd(out, red[0] + red[1] + red[2] + red[3]);
}

extern "C" void kernel_launch(void* const* d_in, const int* in_sizes, int n_in,
                              void* d_out, int out_size, void* d_ws, size_t ws_size,
                              hipStream_t stream) {
    const float* x = (const float*)d_in[0];
    const float* y = (const float*)d_in[1];
    float* out = (float*)d_out;
    char* ws = (char*)d_ws;

    u16* xb = (u16*)(ws + OFF_XB);
    u16* yb = (u16*)(ws + OFF_YB);
    float* x2 = (float*)(ws + OFF_X2);
    float* y2 = (float*)(ws + OFF_Y2);
    float* part = (float*)(ws + OFF_PART);

    prep_kernel<<<dim3(1024, 2), 256, 0, stream>>>(x, y, xb, yb, x2, y2, out);
    softmin_fused<<<2048, 256, 0, stream>>>(xb, yb, x2, y2, part);
    merge_kernel<<<128, 256, 0, stream>>>(part, out);
}

// Round 12
// 104.165 us; speedup vs baseline: 1.7249x; 1.7249x over previous
//
#include <hip/hip_runtime.h>
#include <math.h>

#define BATCH 4
#define NPTS 4096
#define DF 64
#define ROWB 128               // bytes per point row in bf16
#define CT 16                  // cols per tile (one ring slot)
#define CW 512                 // cols per chunk
#define NIT (CW / CT)          // 32 tiles per pass
#define MC 8                   // col chunks
#define RB 64                  // rows per block (2 waves x 32)
#define INV_T 100.0f
#define MARGIN 0.16f           // skipped weights < exp(-16) ~ 1.1e-7
#define HM2C (0.5f * MARGIN * MARGIN)
#define SCALE (1.0f / 16384.0f)

typedef float  f32x4 __attribute__((ext_vector_type(4)));
typedef short  s16x8 __attribute__((ext_vector_type(8)));
typedef unsigned short u16;

// ws layout (~7.3 MB)
#define SZ_B   (BATCH * NPTS * DF * 2)   // bf16 array: 2 MB
#define SZ_N   (BATCH * NPTS * 4)        // norm array: 64 KB
#define OFF_XB 0
#define OFF_YB (OFF_XB + SZ_B)
#define OFF_X2 (OFF_YB + SZ_B)
#define OFF_Y2 (OFF_X2 + SZ_N)
#define OFF_PART (OFF_Y2 + SZ_N)         // [dirb][MC][NPTS][3] floats: 3 MB

__device__ __forceinline__ u16 f2bf(float f) {
    unsigned u = __float_as_uint(f);
    unsigned r = (u + 0x7fffu + ((u >> 16) & 1u)) >> 16;   // RNE
    return (u16)r;
}

// async 16B global -> LDS (DMA, no VGPR round-trip)
__device__ __forceinline__ void async16(void* lds, const void* g) {
    __builtin_amdgcn_global_load_lds(
        (const __attribute__((address_space(1))) unsigned int*)g,
        (__attribute__((address_space(3))) unsigned int*)lds, 16, 0, 0);
}

// fp32 -> bf16 (XOR-swizzled row layout: byte ^= (point&7)<<4) + fp32 norms.
__global__ __launch_bounds__(256) void prep_kernel(const float* __restrict__ X,
                                                   const float* __restrict__ Y,
                                                   u16* __restrict__ xb, u16* __restrict__ yb,
                                                   float* __restrict__ x2, float* __restrict__ y2,
                                                   float* __restrict__ out) {
    if (blockIdx.x == 0 && blockIdx.y == 0 && threadIdx.x == 0) out[0] = 0.0f;
    const float* src = blockIdx.y ? Y : X;
    u16* dstb   = blockIdx.y ? yb : xb;
    float* dstn = blockIdx.y ? y2 : x2;
    int g = blockIdx.x * 256 + threadIdx.x;
    int p = g >> 4;                       // point 0..16383
    int sub = g & 15;                     // 8B chunk within row
    float4 v = ((const float4*)src)[(size_t)p * 16 + sub];
    float n4 = v.x * v.x + v.y * v.y + v.z * v.z + v.w * v.w;
    #pragma unroll
    for (int m = 1; m < 16; m <<= 1) n4 += __shfl_xor(n4, m, 16);
    ushort4 hh;
    hh.x = f2bf(v.x); hh.y = f2bf(v.y); hh.z = f2bf(v.z); hh.w = f2bf(v.w);
    int byteoff = (sub << 3) ^ ((p & 7) << 4);   // swizzle (XOR bits 4..6)
    *(ushort4*)((char*)dstb + (size_t)p * ROWB + byteoff) = hh;
    if (sub == 0) dstn[p] = n4;
}

// Two-phase partial softmin. Block = 2 waves x (32 rows x 512 cols).
// 16-col tiles DMA'd into a 4-slot LDS ring; counted-vmcnt + raw s_barrier
// keeps 2 tiles in flight (never drains to 0 in-loop). All loop scalars from
// LDS => no VGPR-bound global loads in the loop. MFMA C seeded with -y2/2.
__global__ __launch_bounds__(128) void softmin_fused(const u16* __restrict__ xb,
                                                     const u16* __restrict__ yb,
                                                     const float* __restrict__ x2g,
                                                     const float* __restrict__ y2g,
                                                     float* __restrict__ part) {
    __shared__ u16 ring[4][CT * DF];     // 4 x 2 KB
    __shared__ float cyS[CW];            // 2 KB: col norms for this chunk
    __shared__ float x2S[RB];            // 256 B: row norms for this block

    const int tid = threadIdx.x;
    // XCD swizzle: bid&7 = dirb -> each XCD works one (dir,b), ~1MB L2 set.
    const int bid  = blockIdx.x;
    const int dirb = bid & 7;
    const int rem  = bid >> 3;           // 0..511
    const int rowT = rem >> 3;           // 0..63
    const int cs   = rem & 7;            // 0..7
    const int b    = dirb & 3;
    const int dir  = dirb >> 2;

    const int w = tid >> 6;              // wave 0/1 -> rows w*32..+31
    const int h = (tid >> 4) & 3;        // k-octet / D-row group
    const int c = tid & 15;              // fragment lane slot

    const u16 *rowsrc, *colsrc; const float *rn, *cn;
    if (dir == 0) { rowsrc = xb; colsrc = yb; rn = x2g; cn = y2g; }
    else          { rowsrc = yb; colsrc = xb; rn = y2g; cn = x2g; }

    const size_t bpts = (size_t)b * NPTS;
    const char* rbase = (const char*)(rowsrc + (bpts + (size_t)rowT * RB) * DF);
    const char* cbase = (const char*)(colsrc + (bpts + (size_t)cs * CW) * DF);
    const float* cnb = cn + bpts + (size_t)cs * CW;
    const float* rnb = rn + bpts + (size_t)rowT * RB;

    // ---- prologue: stage col/row norms to LDS ----
    *(float4*)&cyS[tid * 4] = ((const float4*)cnb)[tid];
    if (tid < 16) *(float4*)&x2S[tid * 4] = ((const float4*)rnb)[tid];

    // A fragments (persistent, direct from pre-swizzled global): rows w*32+st*16+c
    s16x8 af[2][2];
    #pragma unroll
    for (int st = 0; st < 2; ++st) {
        int rr = w * 32 + st * 16 + c;
        #pragma unroll
        for (int kp = 0; kp < 2; ++kp) {
            int o = (h * 16 + kp * 64) ^ ((c & 7) << 4);
            af[st][kp] = *(const s16x8*)(rbase + rr * ROWB + o);
        }
    }
    // B fragment byte-offsets within a 2KB tile (col point = c)
    const int bo0 = c * ROWB + ((h * 16) ^ ((c & 7) << 4));
    const int bo1 = c * ROWB + ((h * 16 + 64) ^ ((c & 7) << 4));

    __syncthreads();   // cyS/x2S visible (drains prologue loads; one-time)

    #define STAGE(t) async16((char*)ring + ((t) & 3) * (CT * ROWB) + tid * 16, \
                             cbase + (size_t)(t) * (CT * ROWB) + tid * 16)
    STAGE(0); STAGE(1);

    float mx[2][4];
    #pragma unroll
    for (int st = 0; st < 2; ++st)
        #pragma unroll
        for (int r = 0; r < 4; ++r) mx[st][r] = -INFINITY;

    // ================= PASS 1: chunk max of u = x.y - y2/2 =================
    #pragma unroll 4
    for (int it = 0; it < NIT; ++it) {
        asm volatile("s_waitcnt vmcnt(1)" ::: "memory");  // tile(it) landed
        __builtin_amdgcn_s_barrier();
        __builtin_amdgcn_sched_barrier(0);
        if (it + 2 < NIT) STAGE(it + 2);                  // 2-deep prefetch
        const char* bp = (const char*)ring + (it & 3) * (CT * ROWB);
        s16x8 b0 = *(const s16x8*)(bp + bo0);
        s16x8 b1 = *(const s16x8*)(bp + bo1);
        float m0 = -0.5f * cyS[it * CT + c];
        f32x4 seed = {m0, m0, m0, m0};
        #pragma unroll
        for (int st = 0; st < 2; ++st) {
            f32x4 a = __builtin_amdgcn_mfma_f32_16x16x32_bf16(af[st][0], b0, seed, 0, 0, 0);
            a = __builtin_amdgcn_mfma_f32_16x16x32_bf16(af[st][1], b1, a, 0, 0, 0);
            #pragma unroll
            for (int r = 0; r < 4; ++r)
                mx[st][r] = fmaxf(mx[st][r], a[r]);
        }
    }
    asm volatile("s_waitcnt vmcnt(0)" ::: "memory");
    __builtin_amdgcn_s_barrier();

    // butterfly max across 16 col-lanes (rows are wave-exclusive: exact chunk min)
    float gthr[2][4], ssum[2][4], tsum[2][4];
    #pragma unroll
    for (int st = 0; st < 2; ++st)
        #pragma unroll
        for (int r = 0; r < 4; ++r) {
            #pragma unroll
            for (int m = 1; m < 16; m <<= 1)
                mx[st][r] = fmaxf(mx[st][r], __shfl_xor(mx[st][r], m, 16));
            float xv = x2S[w * 32 + st * 16 + 4 * h + r];
            float d2m = fmaf(-2.f, mx[st][r], xv);         // exact min d^2
            float mval = sqrtf(fmaxf(d2m, 0.f));
            gthr[st][r] = mx[st][r] - MARGIN * mval - HM2C;  // u>gthr <=> d<mval+M
            ssum[st][r] = 0.f; tsum[st][r] = 0.f;
        }

    STAGE(0); STAGE(1);

    // ================= PASS 2: gated weighted sums (exp ref = d_thr) =================
    #pragma unroll 4
    for (int it = 0; it < NIT; ++it) {
        asm volatile("s_waitcnt vmcnt(1)" ::: "memory");
        __builtin_amdgcn_s_barrier();
        __builtin_amdgcn_sched_barrier(0);
        if (it + 2 < NIT) STAGE(it + 2);
        const char* bp = (const char*)ring + (it & 3) * (CT * ROWB);
        s16x8 b0 = *(const s16x8*)(bp + bo0);
        s16x8 b1 = *(const s16x8*)(bp + bo1);
        float m0 = -0.5f * cyS[it * CT + c];
        f32x4 seed = {m0, m0, m0, m0};
        #pragma unroll
        for (int st = 0; st < 2; ++st) {
            f32x4 a = __builtin_amdgcn_mfma_f32_16x16x32_bf16(af[st][0], b0, seed, 0, 0, 0);
            a = __builtin_amdgcn_mfma_f32_16x16x32_bf16(af[st][1], b1, a, 0, 0, 0);
            #pragma unroll
            for (int r = 0; r < 4; ++r) {
                if (__any(a[r] > gthr[st][r])) {           // 4 rows x 16 cols, rare
                    float xv = x2S[w * 32 + st * 16 + 4 * h + r];
                    float d2 = fmaf(-2.f, a[r], xv);
                    float d = sqrtf(fmaxf(d2, 0.f));
                    float dthr = sqrtf(fmaf(-2.f, gthr[st][r], xv));   // = mval+M
                    float e = __expf(INV_T * (dthr - d));  // <= e^16, ->0 if far
                    ssum[st][r] += e;
                    tsum[st][r] = fmaf(e, d, tsum[st][r]);
                }
            }
        }
    }
    #undef STAGE

    // butterfly sums across 16 col-lanes; write partial state {dthr, s, t}
    #pragma unroll
    for (int st = 0; st < 2; ++st)
        #pragma unroll
        for (int r = 0; r < 4; ++r)
            #pragma unroll
            for (int m = 1; m < 16; m <<= 1) {
                ssum[st][r] += __shfl_xor(ssum[st][r], m, 16);
                tsum[st][r] += __shfl_xor(tsum[st][r], m, 16);
            }
    if (c == 0) {
        #pragma unroll
        for (int st = 0; st < 2; ++st)
            #pragma unroll
            for (int r = 0; r < 4; ++r) {
                float xv = x2S[w * 32 + st * 16 + 4 * h + r];
                float dthr = sqrtf(fmaf(-2.f, gthr[st][r], xv));
                int row = rowT * RB + w * 32 + st * 16 + 4 * h + r;
                size_t idx = (((size_t)dirb * MC + cs) * NPTS + row) * 3;
                part[idx + 0] = dthr;
                part[idx + 1] = ssum[st][r];
                part[idx + 2] = tsum[st][r];
            }
    }
}

// Merge MC partial states per row, cube, reduce, atomicAdd into out[0].
__global__ __launch_bounds__(256) void merge_kernel(const float* __restrict__ part,
                                                    float* __restrict__ out) {
    __shared__ float red[4];
    int g = blockIdx.x * 256 + threadIdx.x;   // dirb*4096 + row
    int dirb = g >> 12;
    int row  = g & 4095;
    float nm = INFINITY;
    float mnv[MC], sv[MC], tv[MC];
    #pragma unroll
    for (int k = 0; k < MC; ++k) {
        const float* p = part + (((size_t)dirb * MC + k) * NPTS + row) * 3;
        mnv[k] = p[0]; sv[k] = p[1]; tv[k] = p[2];
        nm = fminf(nm, mnv[k]);
    }
    float S = 0.f, T = 0.f;
    #pragma unroll
    for (int k = 0; k < MC; ++k) {
        float cw = __expf(INV_T * (nm - mnv[k]));
        S += sv[k] * cw;
        T += tv[k] * cw;
    }
    float sm = T / S;
    float v = sm * sm * sm * SCALE;
    #pragma unroll
    for (int m = 1; m < 64; m <<= 1) v += __shfl_xor(v, m, 64);
    if ((threadIdx.x & 63) == 0) red[threadIdx.x >> 6] = v;
    __syncthreads();
    if (threadIdx.x == 0) atomicAdd(out, red[0] + red[1] + red[2] + red[3]);
}

extern "C" void kernel_launch(void* const* d_in, const int* in_sizes, int n_in,
                              void* d_out, int out_size, void* d_ws, size_t ws_size,
                              hipStream_t stream) {
    const float* x = (const float*)d_in[0];
    const float* y = (const float*)d_in[1];
    float* out = (float*)d_out;
    char* ws = (char*)d_ws;

    u16* xb = (u16*)(ws + OFF_XB);
    u16* yb = (u16*)(ws + OFF_YB);
    float* x2 = (float*)(ws + OFF_X2);
    float* y2 = (float*)(ws + OFF_Y2);
    float* part = (float*)(ws + OFF_PART);

    prep_kernel<<<dim3(1024, 2), 256, 0, stream>>>(x, y, xb, yb, x2, y2, out);
    softmin_fused<<<4096, 128, 0, stream>>>(xb, yb, x2, y2, part);
    merge_kernel<<<128, 256, 0, stream>>>(part, out);
}

// Round 13
// 85.310 us; speedup vs baseline: 2.1062x; 1.2210x over previous
//
#include <hip/hip_runtime.h>
#include <math.h>

#define BATCH 4
#define NPTS 4096
#define DF 64
#define ROWB 128               // bytes per point row in bf16
#define TILE 64                // col tile per iter
#define MC 4                   // col chunks
#define CHUNK (NPTS / MC)      // 1024
#define ITERS (CHUNK / TILE)   // 16
#define INV_T 100.0f
#define MARGIN 0.16f           // skipped weights < exp(-16) ~ 1.1e-7
#define HM2C (0.5f * MARGIN * MARGIN)
#define SCALE (1.0f / 16384.0f)

typedef float  f32x4 __attribute__((ext_vector_type(4)));
typedef short  s16x8 __attribute__((ext_vector_type(8)));
typedef unsigned short u16;

// ws layout (6.19 MB, proven)
#define SZ_B   (BATCH * NPTS * DF * 2)   // bf16 array: 2 MB
#define SZ_N   (BATCH * NPTS * 4)        // norm array: 64 KB
#define OFF_XB 0
#define OFF_YB (OFF_XB + SZ_B)
#define OFF_X2 (OFF_YB + SZ_B)
#define OFF_Y2 (OFF_X2 + SZ_N)
#define OFF_PART (OFF_Y2 + SZ_N)         // [dirb][MC][NPTS][4] floats: 2 MB

__device__ __forceinline__ u16 f2bf(float f) {
    unsigned u = __float_as_uint(f);
    unsigned r = (u + 0x7fffu + ((u >> 16) & 1u)) >> 16;   // RNE
    return (u16)r;
}

// async 16B global -> LDS (DMA, no VGPR round-trip)
__device__ __forceinline__ void async16(void* lds, const void* g) {
    __builtin_amdgcn_global_load_lds(
        (const __attribute__((address_space(1))) unsigned int*)g,
        (__attribute__((address_space(3))) unsigned int*)lds, 16, 0, 0);
}

// fp32 -> bf16 (XOR-swizzled row layout: byte ^= (point&7)<<4) + fp32 norms.
__global__ __launch_bounds__(256) void prep_kernel(const float* __restrict__ X,
                                                   const float* __restrict__ Y,
                                                   u16* __restrict__ xb, u16* __restrict__ yb,
                                                   float* __restrict__ x2, float* __restrict__ y2,
                                                   float* __restrict__ out) {
    if (blockIdx.x == 0 && blockIdx.y == 0 && threadIdx.x == 0) out[0] = 0.0f;
    const float* src = blockIdx.y ? Y : X;
    u16* dstb   = blockIdx.y ? yb : xb;
    float* dstn = blockIdx.y ? y2 : x2;
    int g = blockIdx.x * 256 + threadIdx.x;
    int p = g >> 4;                       // point 0..16383
    int sub = g & 15;                     // 8B chunk within row
    float4 v = ((const float4*)src)[(size_t)p * 16 + sub];
    float n4 = v.x * v.x + v.y * v.y + v.z * v.z + v.w * v.w;
    #pragma unroll
    for (int m = 1; m < 16; m <<= 1) n4 += __shfl_xor(n4, m, 16);
    ushort4 hh;
    hh.x = f2bf(v.x); hh.y = f2bf(v.y); hh.z = f2bf(v.z); hh.w = f2bf(v.w);
    int byteoff = (sub << 3) ^ ((p & 7) << 4);   // swizzle (XOR bits 4..6)
    *(ushort4*)((char*)dstb + (size_t)p * ROWB + byteoff) = hh;
    if (sub == 0) dstn[p] = n4;
}

// Two-phase partial softmin (R8 skeleton). Block = 64 rows x 1024 cols.
// Wave tiling 2x2. Pass 1: chunk max of u (C seeded with -y2/2) + per-tile
// wave maxes recorded to LDS. Pass 2: tiles with wmax <= gstar skipped whole.
__global__ __launch_bounds__(256, 4) void softmin_fused(const u16* __restrict__ xb,
                                                        const u16* __restrict__ yb,
                                                        const float* __restrict__ x2g,
                                                        const float* __restrict__ y2g,
                                                        float* __restrict__ part) {
    __shared__ u16 ys[2][TILE * DF];     // 2 x 8 KB double buffer
    __shared__ float cyS[CHUNK];         // 4 KB col norms
    __shared__ float xchg[4][32][2];
    __shared__ float wmaxS[4][ITERS];    // per-wave per-tile max u

    const int tid = threadIdx.x;
    const int nt  = blockIdx.x;
    const int b   = blockIdx.y & 3;
    const int cs  = blockIdx.y >> 2;
    const int dir = blockIdx.z;

    const u16 *rowsrc, *colsrc; const float *rn, *cn;
    if (dir == 0) { rowsrc = xb; colsrc = yb; rn = x2g; cn = y2g; }
    else          { rowsrc = yb; colsrc = xb; rn = y2g; cn = x2g; }

    const int w    = tid >> 6;
    const int wrow = w >> 1, wcol = w & 1;
    const int h    = (tid >> 4) & 3;     // k-octet / D-row group
    const int c    = tid & 15;           // fragment lane slot

    const size_t bpts = (size_t)b * NPTS;
    const int row0 = nt * TILE;
    const char* rbase = (const char*)(rowsrc + (bpts + row0) * DF);
    const char* cbase = (const char*)(colsrc + (bpts + (size_t)cs * CHUNK) * DF);
    const float* cnb = cn + bpts + (size_t)cs * CHUNK;

    // loop-invariant B fragment offsets + col point ids
    int boff[2][2], pty[2];
    #pragma unroll
    for (int ct = 0; ct < 2; ++ct) {
        int p = (wcol * 2 + ct) * 16 + c;
        pty[ct] = p;
        #pragma unroll
        for (int kp = 0; kp < 2; ++kp)
            boff[ct][kp] = p * ROWB + ((h * 16 + kp * 64) ^ ((p & 7) << 4));
    }

    // ---- prologue: DMA first y tile; stage col norms; A-frags from global ----
    #pragma unroll
    for (int q = 0; q < 2; ++q) {
        int e = q * 256 + tid;
        async16((char*)ys[0] + e * 16, cbase + e * 16);
    }
    *(float4*)&cyS[tid * 4] = ((const float4*)cnb)[tid];   // 1024 col norms

    s16x8 afrag[2][2];
    #pragma unroll
    for (int st = 0; st < 2; ++st) {
        int rr = (wrow * 2 + st) * 16 + c;
        #pragma unroll
        for (int kp = 0; kp < 2; ++kp) {
            int o = (h * 16 + kp * 64) ^ ((rr & 7) << 4);
            afrag[st][kp] = *(const s16x8*)(rbase + rr * ROWB + o);
        }
    }
    float x2v[2][4];
    #pragma unroll
    for (int st = 0; st < 2; ++st)
        #pragma unroll
        for (int r = 0; r < 4; ++r)
            x2v[st][r] = rn[bpts + row0 + (wrow * 2 + st) * 16 + 4 * h + r];

    float mx[2][4];
    #pragma unroll
    for (int st = 0; st < 2; ++st)
        #pragma unroll
        for (int r = 0; r < 4; ++r) mx[st][r] = -INFINITY;

    __syncthreads();   // drains DMA + cyS writes

    // ================= PASS 1: chunk max of u = x.y - y2/2 (C-seeded) =======
    for (int it = 0; it < ITERS; ++it) {
        if (it > 0) __syncthreads();     // tile(it) DMA drained
        if (it + 1 < ITERS) {            // issue next tile (overlaps compute)
            const char* nsrc = cbase + (size_t)(it + 1) * TILE * ROWB;
            char* nbuf = (char*)ys[(it + 1) & 1];
            #pragma unroll
            for (int q = 0; q < 2; ++q) {
                int e = q * 256 + tid;
                async16(nbuf + e * 16, nsrc + e * 16);
            }
        }
        const char* bptr = (const char*)ys[it & 1];

        s16x8 bf[2][2];
        #pragma unroll
        for (int ct = 0; ct < 2; ++ct)
            #pragma unroll
            for (int kp = 0; kp < 2; ++kp)
                bf[ct][kp] = *(const s16x8*)(bptr + boff[ct][kp]);
        float wt = -INFINITY;
        #pragma unroll
        for (int st = 0; st < 2; ++st)
            #pragma unroll
            for (int ct = 0; ct < 2; ++ct) {
                float m0 = -0.5f * cyS[it * TILE + pty[ct]];
                f32x4 seed = {m0, m0, m0, m0};
                f32x4 a = __builtin_amdgcn_mfma_f32_16x16x32_bf16(afrag[st][0], bf[ct][0], seed, 0, 0, 0);
                a = __builtin_amdgcn_mfma_f32_16x16x32_bf16(afrag[st][1], bf[ct][1], a, 0, 0, 0);
                #pragma unroll
                for (int r = 0; r < 4; ++r) {
                    mx[st][r] = fmaxf(mx[st][r], a[r]);
                    wt = fmaxf(wt, a[r]);
                }
            }
        // wave-level tile max -> LDS (for pass-2 skip)
        #pragma unroll
        for (int m = 1; m < 64; m <<= 1)
            wt = fmaxf(wt, __shfl_xor(wt, m, 64));
        if ((tid & 63) == 0) wmaxS[w][it] = wt;
    }

    // butterfly max within 16 col-lanes, then share across wcol pair
    #pragma unroll
    for (int st = 0; st < 2; ++st)
        #pragma unroll
        for (int r = 0; r < 4; ++r)
            #pragma unroll
            for (int m = 1; m < 16; m <<= 1)
                mx[st][r] = fmaxf(mx[st][r], __shfl_xor(mx[st][r], m, 16));
    __syncthreads();
    if (c == 0) {
        #pragma unroll
        for (int st = 0; st < 2; ++st)
            #pragma unroll
            for (int r = 0; r < 4; ++r)
                xchg[w][st * 16 + 4 * h + r][0] = mx[st][r];
    }
    __syncthreads();
    #pragma unroll
    for (int st = 0; st < 2; ++st)
        #pragma unroll
        for (int r = 0; r < 4; ++r)
            mx[st][r] = fmaxf(mx[st][r], xchg[w ^ 1][st * 16 + 4 * h + r][0]);

    float mval[2][4], gthr[2][4], ssum[2][4], tsum[2][4];
    float gstar = INFINITY;
    #pragma unroll
    for (int st = 0; st < 2; ++st)
        #pragma unroll
        for (int r = 0; r < 4; ++r) {
            float d2m = fmaf(-2.f, mx[st][r], x2v[st][r]);   // exact min d^2
            mval[st][r] = sqrtf(fmaxf(d2m, 0.f));
            gthr[st][r] = mx[st][r] - MARGIN * mval[st][r] - HM2C;
            ssum[st][r] = 0.f; tsum[st][r] = 0.f;
            gstar = fminf(gstar, gthr[st][r]);
        }
    #pragma unroll
    for (int m = 1; m < 64; m <<= 1)
        gstar = fminf(gstar, __shfl_xor(gstar, m, 64));   // min over wave's rows

    // re-prologue for pass 2
    #pragma unroll
    for (int q = 0; q < 2; ++q) {
        int e = q * 256 + tid;
        async16((char*)ys[0] + e * 16, cbase + e * 16);
    }

    // ================= PASS 2: gated weighted sums, tile-skipped ============
    for (int it = 0; it < ITERS; ++it) {
        __syncthreads();
        if (it + 1 < ITERS) {
            const char* nsrc = cbase + (size_t)(it + 1) * TILE * ROWB;
            char* nbuf = (char*)ys[(it + 1) & 1];
            #pragma unroll
            for (int q = 0; q < 2; ++q) {
                int e = q * 256 + tid;
                async16(nbuf + e * 16, nsrc + e * 16);
            }
        }
        if (wmaxS[w][it] <= gstar) continue;   // whole 32x64 patch below margin
        const char* bptr = (const char*)ys[it & 1];

        s16x8 bf[2][2];
        #pragma unroll
        for (int ct = 0; ct < 2; ++ct)
            #pragma unroll
            for (int kp = 0; kp < 2; ++kp)
                bf[ct][kp] = *(const s16x8*)(bptr + boff[ct][kp]);
        #pragma unroll
        for (int st = 0; st < 2; ++st)
            #pragma unroll
            for (int ct = 0; ct < 2; ++ct) {
                float m0 = -0.5f * cyS[it * TILE + pty[ct]];
                f32x4 seed = {m0, m0, m0, m0};
                f32x4 a = __builtin_amdgcn_mfma_f32_16x16x32_bf16(afrag[st][0], bf[ct][0], seed, 0, 0, 0);
                a = __builtin_amdgcn_mfma_f32_16x16x32_bf16(afrag[st][1], bf[ct][1], a, 0, 0, 0);
                #pragma unroll
                for (int r = 0; r < 4; ++r) {
                    if (__any(a[r] > gthr[st][r])) {   // 4-row x 16-col slice
                        float d2 = fmaf(-2.f, a[r], x2v[st][r]);
                        float d = sqrtf(fmaxf(d2, 0.f));
                        float e = __expf(INV_T * (mval[st][r] - d));  // ->0 if far
                        ssum[st][r] += e;
                        tsum[st][r] = fmaf(e, d, tsum[st][r]);
                    }
                }
            }
    }

    // butterfly sums within 16 col-lanes
    #pragma unroll
    for (int st = 0; st < 2; ++st)
        #pragma unroll
        for (int r = 0; r < 4; ++r)
            #pragma unroll
            for (int m = 1; m < 16; m <<= 1) {
                ssum[st][r] += __shfl_xor(ssum[st][r], m, 16);
                tsum[st][r] += __shfl_xor(tsum[st][r], m, 16);
            }

    // cross-wcol add and partial-state write
    __syncthreads();
    if (c == 0) {
        #pragma unroll
        for (int st = 0; st < 2; ++st)
            #pragma unroll
            for (int r = 0; r < 4; ++r) {
                xchg[w][st * 16 + 4 * h + r][0] = ssum[st][r];
                xchg[w][st * 16 + 4 * h + r][1] = tsum[st][r];
            }
    }
    __syncthreads();
    if (wcol == 0 && c == 0) {
        int dirb = dir * 4 + b;
        #pragma unroll
        for (int st = 0; st < 2; ++st)
            #pragma unroll
            for (int r = 0; r < 4; ++r) {
                int row32 = st * 16 + 4 * h + r;
                float S = ssum[st][r] + xchg[w + 1][row32][0];
                float T = tsum[st][r] + xchg[w + 1][row32][1];
                int row = row0 + wrow * 32 + row32;
                float* pp = part + (((size_t)(dirb * MC + cs)) * NPTS + row) * 4;
                pp[0] = mval[st][r]; pp[1] = S; pp[2] = T;
            }
    }
}

// Merge MC partial states per row, cube, reduce, atomicAdd into out[0].
__global__ __launch_bounds__(256) void merge_kernel(const float* __restrict__ part,
                                                    float* __restrict__ out) {
    __shared__ float red[4];
    int g = blockIdx.x * 256 + threadIdx.x;   // dirb*4096 + row
    int dirb = g >> 12;
    int row  = g & 4095;
    const float* p0 = part + (((size_t)dirb * MC) * NPTS + row) * 4;
    float mnv[MC], sv[MC], tv[MC];
    float nm = INFINITY;
    #pragma unroll
    for (int k = 0; k < MC; ++k) {
        const float* p = p0 + (size_t)k * NPTS * 4;
        mnv[k] = p[0]; sv[k] = p[1]; tv[k] = p[2];
        nm = fminf(nm, mnv[k]);
    }
    float S = 0.f, T = 0.f;
    #pragma unroll
    for (int k = 0; k < MC; ++k) {
        float cw = __expf(INV_T * (nm - mnv[k]));
        S += sv[k] * cw;
        T += tv[k] * cw;
    }
    float sm = T / S;
    float v = sm * sm * sm * SCALE;
    #pragma unroll
    for (int m = 1; m < 64; m <<= 1) v += __shfl_xor(v, m, 64);
    if ((threadIdx.x & 63) == 0) red[threadIdx.x >> 6] = v;
    __syncthreads();
    if (threadIdx.x == 0) atomicAdd(out, red[0] + red[1] + red[2] + red[3]);
}

extern "C" void kernel_launch(void* const* d_in, const int* in_sizes, int n_in,
                              void* d_out, int out_size, void* d_ws, size_t ws_size,
                              hipStream_t stream) {
    const float* x = (const float*)d_in[0];
    const float* y = (const float*)d_in[1];
    float* out = (float*)d_out;
    char* ws = (char*)d_ws;

    u16* xb = (u16*)(ws + OFF_XB);
    u16* yb = (u16*)(ws + OFF_YB);
    float* x2 = (float*)(ws + OFF_X2);
    float* y2 = (float*)(ws + OFF_Y2);
    float* part = (float*)(ws + OFF_PART);

    prep_kernel<<<dim3(1024, 2), 256, 0, stream>>>(x, y, xb, yb, x2, y2, out);
    softmin_fused<<<dim3(NPTS / TILE, 4 * MC, 2), 256, 0, stream>>>(xb, yb, x2, y2, part);
    merge_kernel<<<128, 256, 0, stream>>>(part, out);
}

// Round 14
// 70.376 us; speedup vs baseline: 2.5531x; 1.2122x over previous
//
#include <hip/hip_runtime.h>
#include <math.h>

#define BATCH 4
#define NPTS 4096
#define DF 64
#define ROWB 128               // bytes per point row in bf16
#define TILE 128               // col tile per iter (big: amortize per-iter costs)
#define MC 4                   // col chunks
#define CHUNK (NPTS / MC)      // 1024
#define ITERS (CHUNK / TILE)   // 8
#define INV_T 100.0f
#define MARGIN 0.16f           // skipped weights < exp(-16) ~ 1.1e-7
#define HM2C (0.5f * MARGIN * MARGIN)
#define SCALE (1.0f / 16384.0f)

typedef float  f32x4 __attribute__((ext_vector_type(4)));
typedef short  s16x8 __attribute__((ext_vector_type(8)));
typedef unsigned short u16;

// ws layout (6.19 MB, proven)
#define SZ_B   (BATCH * NPTS * DF * 2)   // bf16 array: 2 MB
#define SZ_N   (BATCH * NPTS * 4)        // norm array: 64 KB
#define OFF_XB 0
#define OFF_YB (OFF_XB + SZ_B)
#define OFF_X2 (OFF_YB + SZ_B)
#define OFF_Y2 (OFF_X2 + SZ_N)
#define OFF_PART (OFF_Y2 + SZ_N)         // [dirb][MC][NPTS][4] floats: 2 MB

__device__ __forceinline__ u16 f2bf(float f) {
    unsigned u = __float_as_uint(f);
    unsigned r = (u + 0x7fffu + ((u >> 16) & 1u)) >> 16;   // RNE
    return (u16)r;
}

// async 16B global -> LDS (DMA, no VGPR round-trip)
__device__ __forceinline__ void async16(void* lds, const void* g) {
    __builtin_amdgcn_global_load_lds(
        (const __attribute__((address_space(1))) unsigned int*)g,
        (__attribute__((address_space(3))) unsigned int*)lds, 16, 0, 0);
}

// fp32 -> bf16 (XOR-swizzled row layout: byte ^= (point&7)<<4) + fp32 norms.
__global__ __launch_bounds__(256) void prep_kernel(const float* __restrict__ X,
                                                   const float* __restrict__ Y,
                                                   u16* __restrict__ xb, u16* __restrict__ yb,
                                                   float* __restrict__ x2, float* __restrict__ y2,
                                                   float* __restrict__ out) {
    if (blockIdx.x == 0 && blockIdx.y == 0 && threadIdx.x == 0) out[0] = 0.0f;
    const float* src = blockIdx.y ? Y : X;
    u16* dstb   = blockIdx.y ? yb : xb;
    float* dstn = blockIdx.y ? y2 : x2;
    int g = blockIdx.x * 256 + threadIdx.x;
    int p = g >> 4;                       // point 0..16383
    int sub = g & 15;                     // 8B chunk within row
    float4 v = ((const float4*)src)[(size_t)p * 16 + sub];
    float n4 = v.x * v.x + v.y * v.y + v.z * v.z + v.w * v.w;
    #pragma unroll
    for (int m = 1; m < 16; m <<= 1) n4 += __shfl_xor(n4, m, 16);
    ushort4 hh;
    hh.x = f2bf(v.x); hh.y = f2bf(v.y); hh.z = f2bf(v.z); hh.w = f2bf(v.w);
    int byteoff = (sub << 3) ^ ((p & 7) << 4);   // swizzle (XOR bits 4..6)
    *(ushort4*)((char*)dstb + (size_t)p * ROWB + byteoff) = hh;
    if (sub == 0) dstn[p] = n4;
}

// Two-phase partial softmin (R8 skeleton, TILE=128). Block = 64 rows x 1024
// cols. Wave tiling 2x2 (wave covers 32 rows x 64 cols per tile). MFMA C
// seeded with -y2/2 (hoisted per-ct) so pass-1 epilogue = 1 fmax/elem and
// pass-2 = 1 cmp/elem. Col norms LDS-staged once.
__global__ __launch_bounds__(256, 4) void softmin_fused(const u16* __restrict__ xb,
                                                        const u16* __restrict__ yb,
                                                        const float* __restrict__ x2g,
                                                        const float* __restrict__ y2g,
                                                        float* __restrict__ part) {
    __shared__ u16 ys[2][TILE * DF];     // 2 x 16 KB double buffer
    __shared__ float cyS[CHUNK];         // 4 KB col norms
    __shared__ float xchg[4][32][2];

    const int tid = threadIdx.x;
    const int nt  = blockIdx.x;
    const int b   = blockIdx.y & 3;
    const int cs  = blockIdx.y >> 2;
    const int dir = blockIdx.z;

    const u16 *rowsrc, *colsrc; const float *rn, *cn;
    if (dir == 0) { rowsrc = xb; colsrc = yb; rn = x2g; cn = y2g; }
    else          { rowsrc = yb; colsrc = xb; rn = y2g; cn = x2g; }

    const int w    = tid >> 6;
    const int wrow = w >> 1, wcol = w & 1;
    const int h    = (tid >> 4) & 3;     // k-octet / D-row group
    const int c    = tid & 15;           // fragment lane slot

    const size_t bpts = (size_t)b * NPTS;
    const int row0 = nt * 64;
    const char* rbase = (const char*)(rowsrc + (bpts + row0) * DF);
    const char* cbase = (const char*)(colsrc + (bpts + (size_t)cs * CHUNK) * DF);
    const float* cnb = cn + bpts + (size_t)cs * CHUNK;

    // loop-invariant B fragment offsets + col point ids (4 x 16-col groups)
    int boff[4][2], pty[4];
    #pragma unroll
    for (int ct = 0; ct < 4; ++ct) {
        int p = wcol * 64 + ct * 16 + c;
        pty[ct] = p;
        #pragma unroll
        for (int kp = 0; kp < 2; ++kp)
            boff[ct][kp] = p * ROWB + ((h * 16 + kp * 64) ^ ((p & 7) << 4));
    }

    // ---- prologue: DMA first y tile; stage col norms; A-frags from global ----
    #pragma unroll
    for (int q = 0; q < 4; ++q) {
        int e = q * 256 + tid;
        async16((char*)ys[0] + e * 16, cbase + e * 16);
    }
    *(float4*)&cyS[tid * 4] = ((const float4*)cnb)[tid];   // 1024 col norms

    s16x8 afrag[2][2];
    #pragma unroll
    for (int st = 0; st < 2; ++st) {
        int rr = (wrow * 2 + st) * 16 + c;
        #pragma unroll
        for (int kp = 0; kp < 2; ++kp) {
            int o = (h * 16 + kp * 64) ^ ((rr & 7) << 4);
            afrag[st][kp] = *(const s16x8*)(rbase + rr * ROWB + o);
        }
    }
    float x2v[2][4];
    #pragma unroll
    for (int st = 0; st < 2; ++st)
        #pragma unroll
        for (int r = 0; r < 4; ++r)
            x2v[st][r] = rn[bpts + row0 + (wrow * 2 + st) * 16 + 4 * h + r];

    float mx[2][4];
    #pragma unroll
    for (int st = 0; st < 2; ++st)
        #pragma unroll
        for (int r = 0; r < 4; ++r) mx[st][r] = -INFINITY;

    __syncthreads();   // drains DMA + cyS writes

    // ================= PASS 1: chunk max of u = x.y - y2/2 (C-seeded) =======
    for (int it = 0; it < ITERS; ++it) {
        if (it > 0) __syncthreads();     // tile(it) DMA drained
        if (it + 1 < ITERS) {            // issue next tile (overlaps compute)
            const char* nsrc = cbase + (size_t)(it + 1) * TILE * ROWB;
            char* nbuf = (char*)ys[(it + 1) & 1];
            #pragma unroll
            for (int q = 0; q < 4; ++q) {
                int e = q * 256 + tid;
                async16(nbuf + e * 16, nsrc + e * 16);
            }
        }
        const char* bptr = (const char*)ys[it & 1];

        #pragma unroll
        for (int ct = 0; ct < 4; ++ct) {
            s16x8 b0 = *(const s16x8*)(bptr + boff[ct][0]);
            s16x8 b1 = *(const s16x8*)(bptr + boff[ct][1]);
            float m0 = -0.5f * cyS[it * TILE + pty[ct]];
            f32x4 seed = {m0, m0, m0, m0};
            #pragma unroll
            for (int st = 0; st < 2; ++st) {
                f32x4 a = __builtin_amdgcn_mfma_f32_16x16x32_bf16(afrag[st][0], b0, seed, 0, 0, 0);
                a = __builtin_amdgcn_mfma_f32_16x16x32_bf16(afrag[st][1], b1, a, 0, 0, 0);
                #pragma unroll
                for (int r = 0; r < 4; ++r)
                    mx[st][r] = fmaxf(mx[st][r], a[r]);   // u = a[r] directly
            }
        }
    }

    // butterfly max within 16 col-lanes, then share across wcol pair
    #pragma unroll
    for (int st = 0; st < 2; ++st)
        #pragma unroll
        for (int r = 0; r < 4; ++r)
            #pragma unroll
            for (int m = 1; m < 16; m <<= 1)
                mx[st][r] = fmaxf(mx[st][r], __shfl_xor(mx[st][r], m, 16));
    __syncthreads();
    if (c == 0) {
        #pragma unroll
        for (int st = 0; st < 2; ++st)
            #pragma unroll
            for (int r = 0; r < 4; ++r)
                xchg[w][st * 16 + 4 * h + r][0] = mx[st][r];
    }
    __syncthreads();
    #pragma unroll
    for (int st = 0; st < 2; ++st)
        #pragma unroll
        for (int r = 0; r < 4; ++r)
            mx[st][r] = fmaxf(mx[st][r], xchg[w ^ 1][st * 16 + 4 * h + r][0]);

    // gate thresholds (mval transient; sums referenced to dthr = mval+MARGIN)
    float gthr[2][4], ssum[2][4], tsum[2][4];
    #pragma unroll
    for (int st = 0; st < 2; ++st)
        #pragma unroll
        for (int r = 0; r < 4; ++r) {
            float d2m = fmaf(-2.f, mx[st][r], x2v[st][r]);   // exact min d^2
            float mval = sqrtf(fmaxf(d2m, 0.f));
            gthr[st][r] = mx[st][r] - MARGIN * mval - HM2C;  // u>gthr <=> d<mval+M
            ssum[st][r] = 0.f; tsum[st][r] = 0.f;
        }

    // re-prologue for pass 2
    #pragma unroll
    for (int q = 0; q < 4; ++q) {
        int e = q * 256 + tid;
        async16((char*)ys[0] + e * 16, cbase + e * 16);
    }

    // ================= PASS 2: gated weighted sums (ref = dthr) =============
    for (int it = 0; it < ITERS; ++it) {
        __syncthreads();                 // drains this tile's DMA
        if (it + 1 < ITERS) {
            const char* nsrc = cbase + (size_t)(it + 1) * TILE * ROWB;
            char* nbuf = (char*)ys[(it + 1) & 1];
            #pragma unroll
            for (int q = 0; q < 4; ++q) {
                int e = q * 256 + tid;
                async16(nbuf + e * 16, nsrc + e * 16);
            }
        }
        const char* bptr = (const char*)ys[it & 1];

        #pragma unroll
        for (int ct = 0; ct < 4; ++ct) {
            s16x8 b0 = *(const s16x8*)(bptr + boff[ct][0]);
            s16x8 b1 = *(const s16x8*)(bptr + boff[ct][1]);
            float m0 = -0.5f * cyS[it * TILE + pty[ct]];
            f32x4 seed = {m0, m0, m0, m0};
            #pragma unroll
            for (int st = 0; st < 2; ++st) {
                f32x4 a = __builtin_amdgcn_mfma_f32_16x16x32_bf16(afrag[st][0], b0, seed, 0, 0, 0);
                a = __builtin_amdgcn_mfma_f32_16x16x32_bf16(afrag[st][1], b1, a, 0, 0, 0);
                #pragma unroll
                for (int r = 0; r < 4; ++r) {
                    if (__any(a[r] > gthr[st][r])) {   // 4-row x 16-col slice, rare
                        float d2 = fmaf(-2.f, a[r], x2v[st][r]);
                        float d = sqrtf(fmaxf(d2, 0.f));
                        float dthr = sqrtf(fmaf(-2.f, gthr[st][r], x2v[st][r]));
                        float e = __expf(INV_T * (dthr - d));  // <= e^16, ->0 if far
                        ssum[st][r] += e;
                        tsum[st][r] = fmaf(e, d, tsum[st][r]);
                    }
                }
            }
        }
    }

    // butterfly sums within 16 col-lanes
    #pragma unroll
    for (int st = 0; st < 2; ++st)
        #pragma unroll
        for (int r = 0; r < 4; ++r)
            #pragma unroll
            for (int m = 1; m < 16; m <<= 1) {
                ssum[st][r] += __shfl_xor(ssum[st][r], m, 16);
                tsum[st][r] += __shfl_xor(tsum[st][r], m, 16);
            }

    // cross-wcol add and partial-state write {dthr, S, T}
    __syncthreads();
    if (c == 0) {
        #pragma unroll
        for (int st = 0; st < 2; ++st)
            #pragma unroll
            for (int r = 0; r < 4; ++r) {
                xchg[w][st * 16 + 4 * h + r][0] = ssum[st][r];
                xchg[w][st * 16 + 4 * h + r][1] = tsum[st][r];
            }
    }
    __syncthreads();
    if (wcol == 0 && c == 0) {
        int dirb = dir * 4 + b;
        #pragma unroll
        for (int st = 0; st < 2; ++st)
            #pragma unroll
            for (int r = 0; r < 4; ++r) {
                int row32 = st * 16 + 4 * h + r;
                float S = ssum[st][r] + xchg[w + 1][row32][0];
                float T = tsum[st][r] + xchg[w + 1][row32][1];
                float dthr = sqrtf(fmaf(-2.f, gthr[st][r], x2v[st][r]));
                int row = row0 + wrow * 32 + row32;
                float* pp = part + (((size_t)(dirb * MC + cs)) * NPTS + row) * 4;
                pp[0] = dthr; pp[1] = S; pp[2] = T;
            }
    }
}

// Merge MC partial states per row (reference-consistent), cube, reduce.
__global__ __launch_bounds__(256) void merge_kernel(const float* __restrict__ part,
                                                    float* __restrict__ out) {
    __shared__ float red[4];
    int g = blockIdx.x * 256 + threadIdx.x;   // dirb*4096 + row
    int dirb = g >> 12;
    int row  = g & 4095;
    const float* p0 = part + (((size_t)dirb * MC) * NPTS + row) * 4;
    float mnv[MC], sv[MC], tv[MC];
    float nm = INFINITY;
    #pragma unroll
    for (int k = 0; k < MC; ++k) {
        const float* p = p0 + (size_t)k * NPTS * 4;
        mnv[k] = p[0]; sv[k] = p[1]; tv[k] = p[2];
        nm = fminf(nm, mnv[k]);
    }
    float S = 0.f, T = 0.f;
    #pragma unroll
    for (int k = 0; k < MC; ++k) {
        float cw = __expf(INV_T * (nm - mnv[k]));
        S += sv[k] * cw;
        T += tv[k] * cw;
    }
    float sm = T / S;
    float v = sm * sm * sm * SCALE;
    #pragma unroll
    for (int m = 1; m < 64; m <<= 1) v += __shfl_xor(v, m, 64);
    if ((threadIdx.x & 63) == 0) red[threadIdx.x >> 6] = v;
    __syncthreads();
    if (threadIdx.x == 0) atomicAdd(out, red[0] + red[1] + red[2] + red[3]);
}

extern "C" void kernel_launch(void* const* d_in, const int* in_sizes, int n_in,
                              void* d_out, int out_size, void* d_ws, size_t ws_size,
                              hipStream_t stream) {
    const float* x = (const float*)d_in[0];
    const float* y = (const float*)d_in[1];
    float* out = (float*)d_out;
    char* ws = (char*)d_ws;

    u16* xb = (u16*)(ws + OFF_XB);
    u16* yb = (u16*)(ws + OFF_YB);
    float* x2 = (float*)(ws + OFF_X2);
    float* y2 = (float*)(ws + OFF_Y2);
    float* part = (float*)(ws + OFF_PART);

    prep_kernel<<<dim3(1024, 2), 256, 0, stream>>>(x, y, xb, yb, x2, y2, out);
    softmin_fused<<<dim3(NPTS / 64, 4 * MC, 2), 256, 0, stream>>>(xb, yb, x2, y2, part);
    merge_kernel<<<128, 256, 0, stream>>>(part, out);
}